// Round 1
// baseline (84.555 us; speedup 1.0000x reference)
//
#include <hip/hip_runtime.h>

#define D_DIM 64
#define N_ROT 128

__global__ __launch_bounds__(256) void givens_kernel(
    const float* __restrict__ x,
    const float* __restrict__ thetas,
    float* __restrict__ out,
    int nrows)
{
    __shared__ float c_tab[N_ROT];
    __shared__ float s_tab[N_ROT];

    const int t = threadIdx.x;
    if (t < N_ROT) {
        float th = thetas[t];
        c_tab[t] = cosf(th);
        s_tab[t] = sinf(th);
    }
    __syncthreads();

    const int row = blockIdx.x * blockDim.x + t;
    if (row >= nrows) return;

    const float* xin = x + (size_t)row * D_DIM;
    float v[D_DIM];

    // Vector loads; unpack to scalar regs with compile-time indices.
    #pragma unroll
    for (int q = 0; q < D_DIM / 4; ++q) {
        float4 tmp = reinterpret_cast<const float4*>(xin)[q];
        v[4*q + 0] = tmp.x;
        v[4*q + 1] = tmp.y;
        v[4*q + 2] = tmp.z;
        v[4*q + 3] = tmp.w;
    }

    // 128 sequential Givens rotations; full unroll -> constant indices -> registers.
    #pragma unroll
    for (int k = 0; k < N_ROT; ++k) {
        const int i = k & (D_DIM - 1);
        const int j = (k + 1) & (D_DIM - 1);
        const float c = c_tab[k];
        const float s = s_tab[k];
        const float xi = v[i];
        const float xj = v[j];
        v[i] = fmaf(c, xi, s * xj);
        v[j] = fmaf(c, xj, -s * xi);
    }

    float* o = out + (size_t)row * D_DIM;
    #pragma unroll
    for (int q = 0; q < D_DIM / 4; ++q) {
        float4 tmp;
        tmp.x = v[4*q + 0];
        tmp.y = v[4*q + 1];
        tmp.z = v[4*q + 2];
        tmp.w = v[4*q + 3];
        reinterpret_cast<float4*>(o)[q] = tmp;
    }
}

extern "C" void kernel_launch(void* const* d_in, const int* in_sizes, int n_in,
                              void* d_out, int out_size, void* d_ws, size_t ws_size,
                              hipStream_t stream) {
    const float* x      = (const float*)d_in[0];
    const float* thetas = (const float*)d_in[1];
    float* out          = (float*)d_out;

    const int nrows = in_sizes[0] / D_DIM;   // 8*4096*16 = 524288
    const int block = 256;
    const int grid  = (nrows + block - 1) / block;

    givens_kernel<<<grid, block, 0, stream>>>(x, thetas, out, nrows);
}

// Round 2
// 54.364 us; speedup vs baseline: 1.5554x; 1.5554x over previous
//
#include <hip/hip_runtime.h>

#define D_DIM 64
#define N_ROT 128

// One wave (64 lanes) per block. Each wave processes chunks of 64 rows:
//   lane l owns row l of the chunk; rows transposed through LDS so all
//   global traffic is lane-contiguous (coalesced), all LDS traffic is at
//   the b128 bank floor via an XOR-16 slot swizzle.
__global__ __launch_bounds__(64) void givens_kernel(
    const float* __restrict__ x,
    const float* __restrict__ thetas,
    float* __restrict__ out,
    int nchunks)
{
    // 64 rows x 64 floats = 16 KiB staging buffer (linear layout, swizzled slots)
    __shared__ __align__(16) float buf[64 * D_DIM];
    __shared__ float2 cs_tab[N_ROT];   // interleaved {cos, sin}, 1 KiB

    const int l = threadIdx.x;         // 0..63
    const int lo16 = l & 15;

    // Per-block cos/sin table (2 transcendental pairs per lane, once per block).
    {
        const float tha = thetas[l];
        const float thb = thetas[l + 64];
        cs_tab[l]      = make_float2(cosf(tha), sinf(tha));
        cs_tab[l + 64] = make_float2(cosf(thb), sinf(thb));
    }
    // Single wave per block: wave-local LDS visibility only needs lgkmcnt drain.
    asm volatile("s_waitcnt lgkmcnt(0)" ::: "memory");

    for (int chunk = blockIdx.x; chunk < nchunks; chunk += gridDim.x) {
        const char* gin  = (const char*)(x   + (size_t)chunk * (64 * D_DIM));
        char*       gout = (char*)      (out + (size_t)chunk * (64 * D_DIM));

        // ---- Stage global -> LDS.
        // LDS linear byte s = q*1024 + l*16 corresponds to row r = q*4 + (l>>4),
        // 16B-slot sl = l&15. We want slot sl to hold global slot g = sl ^ (r&15),
        // so pre-swizzle the per-lane global source address (XOR is an involution;
        // it permutes 16B slots within one 256B row, keeping 64B lines intact).
        #pragma unroll
        for (int q = 0; q < 16; ++q) {
            const int r = q * 4 + (l >> 4);
            const int g = lo16 ^ (r & 15);
            __builtin_amdgcn_global_load_lds(
                (const __attribute__((address_space(1))) void*)(gin + r * 256 + g * 16),
                (__attribute__((address_space(3))) void*)((char*)buf + q * 1024),
                16, 0, 0);
        }
        asm volatile("s_waitcnt vmcnt(0)" ::: "memory");

        // ---- Gather own row (swizzled ds_read_b128: even 8-lane/bank-slot spread).
        float v[D_DIM];
        #pragma unroll
        for (int g = 0; g < 16; ++g) {
            const int sl = g ^ lo16;
            const float4 t = *reinterpret_cast<const float4*>(&buf[l * D_DIM + sl * 4]);
            v[4 * g + 0] = t.x; v[4 * g + 1] = t.y;
            v[4 * g + 2] = t.z; v[4 * g + 3] = t.w;
        }

        // ---- 128 chained Givens rotations, fully unrolled -> registers.
        #pragma unroll
        for (int k = 0; k < N_ROT; ++k) {
            const int i = k & (D_DIM - 1);
            const int j = (k + 1) & (D_DIM - 1);
            const float2 cs = cs_tab[k];
            const float xi = v[i], xj = v[j];
            v[i] = fmaf(cs.x, xi,  cs.y * xj);
            v[j] = fmaf(cs.x, xj, -cs.y * xi);
        }

        // ---- Write row back to LDS (same swizzle).
        #pragma unroll
        for (int g = 0; g < 16; ++g) {
            const int sl = g ^ lo16;
            float4 t;
            t.x = v[4 * g + 0]; t.y = v[4 * g + 1];
            t.z = v[4 * g + 2]; t.w = v[4 * g + 3];
            *reinterpret_cast<float4*>(&buf[l * D_DIM + sl * 4]) = t;
        }
        asm volatile("s_waitcnt lgkmcnt(0)" ::: "memory");

        // ---- Drain: linear LDS read, swizzled (still line-coalesced) global store.
        #pragma unroll
        for (int q = 0; q < 16; ++q) {
            const int r = q * 4 + (l >> 4);
            const int g = lo16 ^ (r & 15);
            const float4 t = *reinterpret_cast<const float4*>(&buf[q * 256 + l * 4]);
            *reinterpret_cast<float4*>(gout + r * 256 + g * 16) = t;
        }
    }
}

extern "C" void kernel_launch(void* const* d_in, const int* in_sizes, int n_in,
                              void* d_out, int out_size, void* d_ws, size_t ws_size,
                              hipStream_t stream) {
    const float* x      = (const float*)d_in[0];
    const float* thetas = (const float*)d_in[1];
    float* out          = (float*)d_out;

    const int nrows   = in_sizes[0] / D_DIM;   // 8*4096*16 = 524288
    const int nchunks = nrows / 64;            // 8192 (exact)

    // 9 blocks/CU resident (17 KiB LDS each) x 256 CUs; grid-stride the rest.
    int grid = 9 * 256;
    if (grid > nchunks) grid = nchunks;

    givens_kernel<<<grid, 64, 0, stream>>>(x, thetas, out, nchunks);
}

// Round 3
// 49.760 us; speedup vs baseline: 1.6993x; 1.0925x over previous
//
#include <hip/hip_runtime.h>

#define D_DIM 64
#define N_ROT 128

// One wave (64 lanes) per block; lane l owns row l of a 64-row chunk.
// Software-pipelined: loads for chunk t+1 (and t+2) are in flight while
// chunk t computes; counted vmcnt so stores are never waited on.
__global__ __launch_bounds__(64) void givens_kernel(
    const float* __restrict__ x,
    const float* __restrict__ thetas,
    float* __restrict__ out,
    int nchunks)
{
    __shared__ __align__(16) float bufA[64 * D_DIM];   // load staging  (16 KiB)
    __shared__ __align__(16) float bufB[64 * D_DIM];   // store staging (16 KiB)
    __shared__ float2 cs_tab[N_ROT];                   // {cos,sin}, 1 KiB

    const int l    = threadIdx.x;    // 0..63
    const int lo16 = l & 15;

    {   // per-block cos/sin table
        const float tha = thetas[l];
        const float thb = thetas[l + 64];
        cs_tab[l]      = make_float2(cosf(tha), sinf(tha));
        cs_tab[l + 64] = make_float2(cosf(thb), sinf(thb));
    }
    asm volatile("s_waitcnt lgkmcnt(0)" ::: "memory");

    // Contiguous chunk range per block (streaming-friendly).
    const int cpb = (nchunks + gridDim.x - 1) / gridDim.x;
    const int c0  = blockIdx.x * cpb;
    const int c1  = (c0 + cpb < nchunks) ? (c0 + cpb) : nchunks;
    if (c0 >= c1) return;

    // Stage chunk -> bufA: linear LDS dest, XOR-pre-swizzled global source
    // (involution on 16B slots within each 256B row; 64B lines stay intact).
    auto STAGE = [&](int c) {
        const char* g = (const char*)(x + (size_t)c * (64 * D_DIM));
        #pragma unroll
        for (int q = 0; q < 16; ++q) {
            const int r  = q * 4 + (l >> 4);
            const int gs = lo16 ^ (r & 15);
            __builtin_amdgcn_global_load_lds(
                (const __attribute__((address_space(1))) void*)(g + r * 256 + gs * 16),
                (__attribute__((address_space(3))) void*)((char*)bufA + q * 1024),
                16, 0, 0);
        }
    };

    float v[D_DIM];

    // Gather own row from bufA (swizzled ds_read_b128, conflict-free).
    auto GATHER = [&]() {
        #pragma unroll
        for (int g = 0; g < 16; ++g) {
            const int sl = g ^ lo16;
            const float4 t = *reinterpret_cast<const float4*>(&bufA[l * D_DIM + sl * 4]);
            v[4 * g + 0] = t.x; v[4 * g + 1] = t.y;
            v[4 * g + 2] = t.z; v[4 * g + 3] = t.w;
        }
    };

    // ---- Prologue: fill regs with chunk c0; put chunk c0+1 in flight.
    STAGE(c0);
    asm volatile("s_waitcnt vmcnt(0)" ::: "memory");
    GATHER();
    asm volatile("s_waitcnt lgkmcnt(0)" ::: "memory");
    if (c0 + 1 < c1) STAGE(c0 + 1);

    for (int c = c0; c < c1; ++c) {
        // ---- 128 chained rotations; 1 dependent fma per rotation on the
        // critical path (stale-operand muls hoist above the chain).
        #pragma unroll
        for (int k = 0; k < N_ROT; ++k) {
            const int i = k & (D_DIM - 1);
            const int j = (k + 1) & (D_DIM - 1);
            const float2 cs = cs_tab[k];
            const float xi = v[i], xj = v[j];
            v[i] = fmaf(cs.x, xi, cs.y * xj);    // c*xi? no: s*xj early, dep-fma on xi
            v[j] = fmaf(-cs.y, xi, cs.x * xj);   // c*xj early, dep-fma on xi
        }

        // ---- Transpose out through bufB (same swizzle).
        #pragma unroll
        for (int g = 0; g < 16; ++g) {
            const int sl = g ^ lo16;
            float4 t;
            t.x = v[4 * g + 0]; t.y = v[4 * g + 1];
            t.z = v[4 * g + 2]; t.w = v[4 * g + 3];
            *reinterpret_cast<float4*>(&bufB[l * D_DIM + sl * 4]) = t;
        }
        asm volatile("s_waitcnt lgkmcnt(0)" ::: "memory");

        // ---- Drain bufB -> global (linear LDS read, line-coalesced stores).
        {
            char* gout = (char*)(out + (size_t)c * (64 * D_DIM));
            #pragma unroll
            for (int q = 0; q < 16; ++q) {
                const int r  = q * 4 + (l >> 4);
                const int gs = lo16 ^ (r & 15);
                const float4 t = *reinterpret_cast<const float4*>(&bufB[q * 256 + l * 4]);
                *reinterpret_cast<float4*>(gout + r * 256 + gs * 16) = t;
            }
        }

        if (c + 1 < c1) {
            // Queue (FIFO): L(c+1)[16] then S(c)[16]. vmcnt(16) retires all of
            // L(c+1) while leaving the 16 stores in flight.
            asm volatile("s_waitcnt vmcnt(16)" ::: "memory");
            GATHER();
            asm volatile("s_waitcnt lgkmcnt(0)" ::: "memory");  // bufA free
            if (c + 2 < c1) STAGE(c + 2);
        }
    }
}

extern "C" void kernel_launch(void* const* d_in, const int* in_sizes, int n_in,
                              void* d_out, int out_size, void* d_ws, size_t ws_size,
                              hipStream_t stream) {
    const float* x      = (const float*)d_in[0];
    const float* thetas = (const float*)d_in[1];
    float* out          = (float*)d_out;

    const int nrows   = in_sizes[0] / D_DIM;   // 524288
    const int nchunks = nrows / 64;            // 8192

    // 4 blocks/CU resident (33.5 KiB LDS each) x 256 CUs.
    int grid = 4 * 256;
    if (grid > nchunks) grid = nchunks;

    givens_kernel<<<grid, 64, 0, stream>>>(x, thetas, out, nchunks);
}

// Round 4
// 48.639 us; speedup vs baseline: 1.7384x; 1.0230x over previous
//
#include <hip/hip_runtime.h>

#define D_DIM 64
#define N_ROT 128

typedef float v4f __attribute__((ext_vector_type(4)));

// One wave (64 lanes) per block; lane l owns row l of a 64-row chunk.
// Software-pipelined: loads for chunk t+1 (and t+2) are in flight while
// chunk t computes; counted vmcnt so stores are never waited on.
// Drain stores are non-temporal: output is write-once, keep it out of
// L2/L3 so the (re-read) input stays Infinity-Cache-resident.
__global__ __launch_bounds__(64) void givens_kernel(
    const float* __restrict__ x,
    const float* __restrict__ thetas,
    float* __restrict__ out,
    int nchunks)
{
    __shared__ __align__(16) float bufA[64 * D_DIM];   // load staging  (16 KiB)
    __shared__ __align__(16) float bufB[64 * D_DIM];   // store staging (16 KiB)
    __shared__ float2 cs_tab[N_ROT];                   // {cos,sin}, 1 KiB

    const int l    = threadIdx.x;    // 0..63
    const int lo16 = l & 15;

    {   // per-block cos/sin table
        const float tha = thetas[l];
        const float thb = thetas[l + 64];
        cs_tab[l]      = make_float2(cosf(tha), sinf(tha));
        cs_tab[l + 64] = make_float2(cosf(thb), sinf(thb));
    }
    asm volatile("s_waitcnt lgkmcnt(0)" ::: "memory");

    // Contiguous chunk range per block (streaming-friendly).
    const int cpb = (nchunks + gridDim.x - 1) / gridDim.x;
    const int c0  = blockIdx.x * cpb;
    const int c1  = (c0 + cpb < nchunks) ? (c0 + cpb) : nchunks;
    if (c0 >= c1) return;

    // Stage chunk -> bufA: linear LDS dest, XOR-pre-swizzled global source
    // (involution on 16B slots within each 256B row; 64B lines stay intact).
    auto STAGE = [&](int c) {
        const char* g = (const char*)(x + (size_t)c * (64 * D_DIM));
        #pragma unroll
        for (int q = 0; q < 16; ++q) {
            const int r  = q * 4 + (l >> 4);
            const int gs = lo16 ^ (r & 15);
            __builtin_amdgcn_global_load_lds(
                (const __attribute__((address_space(1))) void*)(g + r * 256 + gs * 16),
                (__attribute__((address_space(3))) void*)((char*)bufA + q * 1024),
                16, 0, 0);
        }
    };

    float v[D_DIM];

    // Gather own row from bufA (swizzled ds_read_b128, conflict-free).
    auto GATHER = [&]() {
        #pragma unroll
        for (int g = 0; g < 16; ++g) {
            const int sl = g ^ lo16;
            const float4 t = *reinterpret_cast<const float4*>(&bufA[l * D_DIM + sl * 4]);
            v[4 * g + 0] = t.x; v[4 * g + 1] = t.y;
            v[4 * g + 2] = t.z; v[4 * g + 3] = t.w;
        }
    };

    // ---- Prologue: fill regs with chunk c0; put chunk c0+1 in flight.
    STAGE(c0);
    asm volatile("s_waitcnt vmcnt(0)" ::: "memory");
    GATHER();
    asm volatile("s_waitcnt lgkmcnt(0)" ::: "memory");
    if (c0 + 1 < c1) STAGE(c0 + 1);

    for (int c = c0; c < c1; ++c) {
        // ---- 128 chained rotations; 1 dependent fma per rotation on the
        // critical path (the independent muls hoist above the chain).
        #pragma unroll
        for (int k = 0; k < N_ROT; ++k) {
            const int i = k & (D_DIM - 1);
            const int j = (k + 1) & (D_DIM - 1);
            const float2 cs = cs_tab[k];
            const float xi = v[i], xj = v[j];
            v[i] = fmaf(cs.x, xi, cs.y * xj);
            v[j] = fmaf(-cs.y, xi, cs.x * xj);
        }

        // ---- Transpose out through bufB (same swizzle).
        #pragma unroll
        for (int g = 0; g < 16; ++g) {
            const int sl = g ^ lo16;
            float4 t;
            t.x = v[4 * g + 0]; t.y = v[4 * g + 1];
            t.z = v[4 * g + 2]; t.w = v[4 * g + 3];
            *reinterpret_cast<float4*>(&bufB[l * D_DIM + sl * 4]) = t;
        }
        asm volatile("s_waitcnt lgkmcnt(0)" ::: "memory");

        // ---- Drain bufB -> global (linear LDS read, line-coalesced nt stores).
        {
            char* gout = (char*)(out + (size_t)c * (64 * D_DIM));
            #pragma unroll
            for (int q = 0; q < 16; ++q) {
                const int r  = q * 4 + (l >> 4);
                const int gs = lo16 ^ (r & 15);
                const v4f t = *reinterpret_cast<const v4f*>(&bufB[q * 256 + l * 4]);
                __builtin_nontemporal_store(
                    t, reinterpret_cast<v4f*>(gout + r * 256 + gs * 16));
            }
        }

        if (c + 1 < c1) {
            // Queue (FIFO): L(c+1)[16] then S(c)[16]. vmcnt(16) retires all of
            // L(c+1) while leaving the 16 stores in flight.
            asm volatile("s_waitcnt vmcnt(16)" ::: "memory");
            GATHER();
            asm volatile("s_waitcnt lgkmcnt(0)" ::: "memory");  // bufA free
            if (c + 2 < c1) STAGE(c + 2);
        }
    }
}

extern "C" void kernel_launch(void* const* d_in, const int* in_sizes, int n_in,
                              void* d_out, int out_size, void* d_ws, size_t ws_size,
                              hipStream_t stream) {
    const float* x      = (const float*)d_in[0];
    const float* thetas = (const float*)d_in[1];
    float* out          = (float*)d_out;

    const int nrows   = in_sizes[0] / D_DIM;   // 524288
    const int nchunks = nrows / 64;            // 8192

    // 4 blocks/CU resident (33.5 KiB LDS each) x 256 CUs.
    int grid = 4 * 256;
    if (grid > nchunks) grid = nchunks;

    givens_kernel<<<grid, 64, 0, stream>>>(x, thetas, out, nchunks);
}